// Round 12
// baseline (198.039 us; speedup 1.0000x reference)
//
#include <hip/hip_runtime.h>
#include <math.h>

// Problem constants
#define B 16
#define H 1024
#define W 1024
#define TOPK 5000
#define SCORES_TH 0.2f

// selection pipeline constants
#define CAP 65536          // max candidates per batch (expected ~42k)
#define SELCAP 8192        // max selected per batch
#define NB2 9831           // buckets over value bits[31:11]
#define OFFB2 510361       // bits(0.2f) >> 11
#define GS2 9840           // padded per-batch stride for hist/G (>= NB2+2)
#define SCHUNK 10          // ceil(NB2/1024)
#define CSTRIDE 32         // counts padded 128 B apart
#define CBUF 256           // per-tile candidate cap

__device__ __forceinline__ float4 fmax4(float4 a, float4 b) {
    return make_float4(fmaxf(a.x, b.x), fmaxf(a.y, b.y),
                       fmaxf(a.z, b.z), fmaxf(a.w, b.w));
}

// ---------------------------------------------------------------------------
// K1: single 5x5 NMS (== double NMS, proven identity) + compaction.
// EXACT Round-10 kernel (measured 78 us) — hist fusion reverted.
// Keys: (value_bits << 32) | ~idx  (desc value, asc index) — unique per pixel.
// ---------------------------------------------------------------------------
__global__ __launch_bounds__(256) void nms_compact(
    const float* __restrict__ s,
    unsigned* __restrict__ counts,
    unsigned long long* __restrict__ cand)
{
    const int b = blockIdx.z;
    // XCD swizzle: each XCD gets a contiguous 4-tile-row stripe.
    const int lin = blockIdx.y * 32 + blockIdx.x;
    const int xcd = lin & 7, seq = lin >> 3;
    const int x0 = (seq & 31) * 32;
    const int y0 = (xcd * 4 + (seq >> 5)) * 32;
    const float* sb = s + (size_t)b * (H * W);

    __shared__ float sT[36][44];     // rows gy=y0-2..y0+33, cols gx=x0-4..x0+35
    __shared__ float vm[32][44];     // vm[ty][c] = max over sT[ty..ty+4][c]
    __shared__ unsigned long long cbuf[CBUF];
    __shared__ unsigned lcnt, lbase;

    const int tid = threadIdx.x;
    if (tid == 0) lcnt = 0;

    // ---- P1: load 36x40 raw scores (x halo 4 for alignment, y halo 2) -----
    const bool xedge = (x0 == 0) | (x0 + 32 == W);
    if (!xedge) {
        for (int k = tid; k < 36 * 10; k += 256) {
            int row = k / 10, q = k - row * 10;
            int gy = y0 - 2 + row;
            float4 v;
            if (gy >= 0 && gy < H)
                v = *(const float4*)(sb + (size_t)gy * W + (x0 - 4) + 4 * q);
            else
                v = make_float4(-INFINITY, -INFINITY, -INFINITY, -INFINITY);
            *(float4*)&sT[row][4 * q] = v;
        }
    } else {
        for (int k = tid; k < 36 * 40; k += 256) {
            int row = k / 40, col = k - row * 40;
            int gy = y0 - 2 + row, gx = x0 - 4 + col;
            float v = -INFINITY;
            if (gx >= 0 && gx < W && gy >= 0 && gy < H) v = sb[(size_t)gy * W + gx];
            sT[row][col] = v;
        }
    }
    __syncthreads();

    // ---- P2: vertical sliding 5-max, 2 rows/thread ------------------------
    if (tid < 160) {                 // 16 row-groups x 10 col-quads
        int g = tid / 10, q = tid - g * 10;
        int r0 = g * 2, c4 = q * 4;
        float4 s0 = *(float4*)&sT[r0 + 0][c4];
        float4 s1 = *(float4*)&sT[r0 + 1][c4];
        float4 s2 = *(float4*)&sT[r0 + 2][c4];
        float4 s3 = *(float4*)&sT[r0 + 3][c4];
        float4 s4 = *(float4*)&sT[r0 + 4][c4];
        float4 s5 = *(float4*)&sT[r0 + 5][c4];
        float4 p01 = fmax4(s0, s1), p23 = fmax4(s2, s3), p45 = fmax4(s4, s5);
        float4 v0 = fmax4(fmax4(p01, p23), s4);   // max(s0..s4)
        float4 v1 = fmax4(fmax4(p23, p45), s1);   // max(s1..s5)
        *(float4*)&vm[r0 + 0][c4] = v0;
        *(float4*)&vm[r0 + 1][c4] = v1;
    }
    __syncthreads();

    // ---- P3: horizontal 5-max in registers + peak test + emit -------------
    {
        int ty = tid >> 3, tx4 = (tid & 7) * 4;
        float2 va = *(float2*)&vm[ty][tx4 + 2];
        float4 vb = *(float4*)&vm[ty][tx4 + 4];
        float2 vc = *(float2*)&vm[ty][tx4 + 8];
        float a0 = va.x, a1 = va.y, a2 = vb.x, a3 = vb.y,
              a4 = vb.z, a5 = vb.w, a6 = vc.x, a7 = vc.y;
        float p01 = fmaxf(a0, a1), p12 = fmaxf(a1, a2), p23 = fmaxf(a2, a3),
              p34 = fmaxf(a3, a4), p45 = fmaxf(a4, a5), p56 = fmaxf(a5, a6);
        float o0 = fmaxf(fmaxf(p01, p23), a4);
        float o1 = fmaxf(fmaxf(p12, p34), a5);
        float o2 = fmaxf(fmaxf(p23, p45), a6);
        float o3 = fmaxf(fmaxf(p34, p56), a7);
        float4 ctr = *(float4*)&sT[ty + 2][tx4 + 4];
        float o[4] = { o0, o1, o2, o3 };
        float c[4] = { ctr.x, ctr.y, ctr.z, ctr.w };
        #pragma unroll
        for (int j = 0; j < 4; ++j) {
            if (c[j] > SCORES_TH && c[j] == o[j]) {
                unsigned idx = (unsigned)((y0 + ty) * W + (x0 + tx4 + j));
                unsigned long long key =
                    ((unsigned long long)__float_as_uint(c[j]) << 32) | (unsigned)(~idx);
                unsigned p = atomicAdd(&lcnt, 1u);
                if (p < CBUF) cbuf[p] = key;
            }
        }
    }
    __syncthreads();

    // ---- P4: one global atomic per block, coalesced flush -----------------
    unsigned n = lcnt; if (n > CBUF) n = CBUF;
    if (tid == 0) lbase = atomicAdd(&counts[b * CSTRIDE], n);
    __syncthreads();
    unsigned base = lbase;
    for (unsigned k = tid; k < n; k += 256)
        if (base + k < CAP) cand[(size_t)b * CAP + base + k] = cbuf[k];
}

// ---------------------------------------------------------------------------
// K1b: grid-parallel histogram of cand (off K1's critical path).
// ---------------------------------------------------------------------------
__global__ __launch_bounds__(256) void hist_build(
    const unsigned* __restrict__ counts,
    const unsigned long long* __restrict__ cand,
    unsigned* __restrict__ hist)
{
    const int b = blockIdx.y;
    unsigned M = counts[b * CSTRIDE]; if (M > CAP) M = CAP;
    unsigned i = blockIdx.x * 256u + threadIdx.x;
    if (i >= M) return;
    unsigned bits = (unsigned)(cand[(size_t)b * CAP + i] >> 32);
    int bk = (int)(bits >> 11) - OFFB2;
    bk = bk < 0 ? 0 : (bk > NB2 - 1 ? NB2 - 1 : bk);
    atomicAdd(&hist[(size_t)b * GS2 + bk], 1u);
}

// ---------------------------------------------------------------------------
// K2: scan-only: suffix-sum the histogram, find threshold T, publish segment
// table G, selC, Tarr. One block per batch.
// I[bk] = #{keys in buckets >= bk}; segment of bucket bk = [I[bk+1], I[bk]).
// ---------------------------------------------------------------------------
__global__ __launch_bounds__(1024) void scanT(
    const unsigned* __restrict__ hist,
    unsigned* __restrict__ G,
    unsigned* __restrict__ selC,
    unsigned* __restrict__ Tarr)
{
    const int b = blockIdx.x;
    __shared__ unsigned I[NB2 + 2];   // 39.3 KB
    __shared__ unsigned csum[1024];
    __shared__ int Tsh;
    const int tid = threadIdx.x;
    const unsigned* hb = hist + (size_t)b * GS2;

    for (int i = tid; i < NB2 + 2; i += 1024) I[i] = (i < NB2) ? hb[i] : 0u;
    if (tid == 0) Tsh = 0;
    __syncthreads();

    unsigned local = 0;
    #pragma unroll
    for (int u = 0; u < SCHUNK; ++u) {
        int r = tid * SCHUNK + u;
        if (r < NB2) local += I[NB2 - 1 - r];
    }
    csum[tid] = local;
    __syncthreads();
    for (int off = 1; off < 1024; off <<= 1) {      // Hillis-Steele inclusive
        unsigned v = (tid >= off) ? csum[tid - off] : 0u;
        __syncthreads();
        csum[tid] += v;
        __syncthreads();
    }
    unsigned run = (tid == 0) ? 0u : csum[tid - 1];
    #pragma unroll
    for (int u = 0; u < SCHUNK; ++u) {
        int r = tid * SCHUNK + u;
        if (r < NB2) {
            int bk = NB2 - 1 - r;
            run += I[bk];
            I[bk] = run;          // I becomes inclusive suffix sum
        }
    }
    __syncthreads();

    int localT = -1;
    #pragma unroll
    for (int u = 0; u < SCHUNK; ++u) {
        int r = tid * SCHUNK + u;
        if (r < NB2) {
            int bk = NB2 - 1 - r;
            if (I[bk] >= TOPK && bk > localT) localT = bk;
        }
    }
    if (localT >= 0) atomicMax(&Tsh, localT);
    __syncthreads();
    const int T = Tsh;
    if (tid == 0) { selC[b] = I[T]; Tarr[b] = (unsigned)T; }

    unsigned* Gb = G + (size_t)b * GS2;
    for (int i = tid; i < NB2 + 2; i += 1024) Gb[i] = I[i];
}

// ---------------------------------------------------------------------------
// K3: grid-parallel bucket-grouped scatter cand -> sel, cursors ARE G[bk+1].
// After completion G[bk+1] == I_orig[bk] for every bucket with keys >= T
// (empty buckets hold trivially), so K4 recovers segments from mutated G.
// ---------------------------------------------------------------------------
__global__ __launch_bounds__(256) void scatter_sel(
    const unsigned* __restrict__ counts,
    const unsigned long long* __restrict__ cand,
    const unsigned* __restrict__ Tarr,
    unsigned* __restrict__ G,
    unsigned long long* __restrict__ sel)
{
    const int b = blockIdx.y;
    unsigned M = counts[b * CSTRIDE]; if (M > CAP) M = CAP;
    unsigned i = blockIdx.x * 256u + threadIdx.x;
    if (i >= M) return;
    unsigned long long key = cand[(size_t)b * CAP + i];
    unsigned bits = (unsigned)(key >> 32);
    int bk = (int)(bits >> 11) - OFFB2;
    bk = bk < 0 ? 0 : (bk > NB2 - 1 ? NB2 - 1 : bk);
    if (bk >= (int)Tarr[b]) {
        unsigned p = atomicAdd(&G[(size_t)b * GS2 + bk + 1], 1u);
        if (p < SELCAP) sel[(size_t)b * SELCAP + p] = key;
    }
}

// ---------------------------------------------------------------------------
// K4: two-level exact rank, 4 lanes/key. Post-scatter G: start = G[bk+2],
// end = G[bk+1] (== original I[bk+1], I[bk]). Softmax split across lanes.
// ---------------------------------------------------------------------------
__global__ __launch_bounds__(256) void rank_refine(
    const float* __restrict__ s,
    const unsigned long long* __restrict__ sel,
    const unsigned* __restrict__ selC,
    const unsigned* __restrict__ G,
    float* __restrict__ out)
{
    const int b = blockIdx.y;
    unsigned C = selC[b]; if (C > SELCAP) C = SELCAP;
    const int tid = threadIdx.x;
    const unsigned g = blockIdx.x * 64u + (unsigned)(tid >> 2);
    const int l = tid & 3;
    if (g >= C) return;

    const unsigned long long* sb = sel + (size_t)b * SELCAP;
    const unsigned long long my = sb[g];
    unsigned bits = (unsigned)(my >> 32);
    int bk = (int)(bits >> 11) - OFFB2;
    bk = bk < 0 ? 0 : (bk > NB2 - 1 ? NB2 - 1 : bk);

    const unsigned* Gb = G + (size_t)b * GS2;
    unsigned start = Gb[bk + 2], end = Gb[bk + 1];  // post-scatter recovery
    if (end > SELCAP) end = SELCAP;
    unsigned rank = 0;
    for (unsigned j = start + (unsigned)l; j < end; j += 4)
        rank += (sb[j] > my) ? 1u : 0u;

    float v = __uint_as_float(bits);
    unsigned idx = ~((unsigned)my);
    int y = (int)(idx >> 10), x = (int)(idx & 1023);
    const float* smb = s + (size_t)b * (H * W);
    float wsum = 0.f, ox = 0.f, oy = 0.f;
    for (int c = l; c < 25; c += 4) {
        int dy = c / 5 - 2, dx = c - (c / 5) * 5 - 2;
        int yy = y + dy, xx = x + dx;
        bool inb = (yy >= 0 && yy < H && xx >= 0 && xx < W);
        int yc = min(max(yy, 0), H - 1), xc = min(max(xx, 0), W - 1);
        float p = smb[yc * W + xc];
        float lg = inb ? p * 10.0f : -1e9f;   // 1/TEMPERATURE = 10
        float e = expf(lg);
        wsum += e; ox += e * (float)dx; oy += e * (float)dy;
    }
    rank += __shfl_xor(rank, 1); rank += __shfl_xor(rank, 2);
    wsum += __shfl_xor(wsum, 1); wsum += __shfl_xor(wsum, 2);
    ox   += __shfl_xor(ox, 1);   ox   += __shfl_xor(ox, 2);
    oy   += __shfl_xor(oy, 1);   oy   += __shfl_xor(oy, 2);

    unsigned frank = start + rank;
    if (l == 0 && frank < TOPK) {
        float offx = ox / wsum, offy = oy / wsum;
        out[((size_t)b * TOPK + frank) * 2 + 0] = (float)x + offx;
        out[((size_t)b * TOPK + frank) * 2 + 1] = (float)y + offy;
        out[(size_t)B * TOPK * 2 + (size_t)b * TOPK + frank] = v;
    }
}

// ---------------------------------------------------------------------------
extern "C" void kernel_launch(void* const* d_in, const int* in_sizes, int n_in,
                              void* d_out, int out_size, void* d_ws, size_t ws_size,
                              hipStream_t stream)
{
    const float* s = (const float*)d_in[0];
    float* out = (float*)d_out;
    char* ws = (char*)d_ws;

    size_t off = 0;
    unsigned* counts        = (unsigned*)(ws + off);  off += 2048;   // B*CSTRIDE*4
    unsigned* selC          = (unsigned*)(ws + off);  off += 64;
    unsigned* Tarr          = (unsigned*)(ws + off);  off += 64;
    unsigned* G             = (unsigned*)(ws + off);  off += (size_t)B * GS2 * 4;  // 630 KB
    unsigned* hist          = (unsigned*)(ws + off);  off += (size_t)B * GS2 * 4;
    unsigned long long* sel = (unsigned long long*)(ws + off); off += (size_t)B * SELCAP * 8; // 1 MB
    unsigned long long* cand= (unsigned long long*)(ws + off);                     // 8.4 MB

    hipMemsetAsync(counts, 0, 2176, stream);              // counts+selC+Tarr
    hipMemsetAsync(hist, 0, (size_t)B * GS2 * 4, stream);
    hipMemsetAsync(d_out, 0, (size_t)out_size * sizeof(float), stream);

    nms_compact<<<dim3(32, 32, B), dim3(256), 0, stream>>>(s, counts, cand);
    hist_build<<<dim3(CAP / 256, B), dim3(256), 0, stream>>>(counts, cand, hist);
    scanT<<<dim3(B), dim3(1024), 0, stream>>>(hist, G, selC, Tarr);
    scatter_sel<<<dim3(CAP / 256, B), dim3(256), 0, stream>>>(counts, cand, Tarr, G, sel);
    rank_refine<<<dim3(SELCAP * 4 / 256, B), dim3(256), 0, stream>>>(s, sel, selC, G, out);
}

// Round 13
// 133.926 us; speedup vs baseline: 1.4787x; 1.4787x over previous
//
#include <hip/hip_runtime.h>
#include <math.h>

// Problem constants
#define B 16
#define H 1024
#define W 1024
#define TOPK 5000
#define SCORES_TH 0.2f

// selection pipeline constants
#define CAP 65536          // max candidates per batch (expected ~42k)
#define SELCAP 8192        // max selected per batch
#define NB2 9831           // buckets over value bits[31:11]
#define OFFB2 510361       // bits(0.2f) >> 11
#define GS2 9840           // padded per-batch stride for G (>= NB2+1)
#define SCHUNK 10          // ceil(NB2/1024)
#define CSTRIDE 32         // counts padded 128 B apart
#define CBUF 256           // per-tile candidate cap

__device__ __forceinline__ float4 fmax4(float4 a, float4 b) {
    return make_float4(fmaxf(a.x, b.x), fmaxf(a.y, b.y),
                       fmaxf(a.z, b.z), fmaxf(a.w, b.w));
}

// ---------------------------------------------------------------------------
// K1: single 5x5 NMS (== double NMS, proven identity) + compaction.
// FROZEN (measured 80 us in rounds 10/12).
// Keys: (value_bits << 32) | ~idx  (desc value, asc index) — unique per pixel.
// ---------------------------------------------------------------------------
__global__ __launch_bounds__(256) void nms_compact(
    const float* __restrict__ s,
    unsigned* __restrict__ counts,
    unsigned long long* __restrict__ cand)
{
    const int b = blockIdx.z;
    // XCD swizzle: each XCD gets a contiguous 4-tile-row stripe.
    const int lin = blockIdx.y * 32 + blockIdx.x;
    const int xcd = lin & 7, seq = lin >> 3;
    const int x0 = (seq & 31) * 32;
    const int y0 = (xcd * 4 + (seq >> 5)) * 32;
    const float* sb = s + (size_t)b * (H * W);

    __shared__ float sT[36][44];     // rows gy=y0-2..y0+33, cols gx=x0-4..x0+35
    __shared__ float vm[32][44];     // vm[ty][c] = max over sT[ty..ty+4][c]
    __shared__ unsigned long long cbuf[CBUF];
    __shared__ unsigned lcnt, lbase;

    const int tid = threadIdx.x;
    if (tid == 0) lcnt = 0;

    // ---- P1: load 36x40 raw scores (x halo 4 for alignment, y halo 2) -----
    const bool xedge = (x0 == 0) | (x0 + 32 == W);
    if (!xedge) {
        for (int k = tid; k < 36 * 10; k += 256) {
            int row = k / 10, q = k - row * 10;
            int gy = y0 - 2 + row;
            float4 v;
            if (gy >= 0 && gy < H)
                v = *(const float4*)(sb + (size_t)gy * W + (x0 - 4) + 4 * q);
            else
                v = make_float4(-INFINITY, -INFINITY, -INFINITY, -INFINITY);
            *(float4*)&sT[row][4 * q] = v;
        }
    } else {
        for (int k = tid; k < 36 * 40; k += 256) {
            int row = k / 40, col = k - row * 40;
            int gy = y0 - 2 + row, gx = x0 - 4 + col;
            float v = -INFINITY;
            if (gx >= 0 && gx < W && gy >= 0 && gy < H) v = sb[(size_t)gy * W + gx];
            sT[row][col] = v;
        }
    }
    __syncthreads();

    // ---- P2: vertical sliding 5-max, 2 rows/thread ------------------------
    if (tid < 160) {                 // 16 row-groups x 10 col-quads
        int g = tid / 10, q = tid - g * 10;
        int r0 = g * 2, c4 = q * 4;
        float4 s0 = *(float4*)&sT[r0 + 0][c4];
        float4 s1 = *(float4*)&sT[r0 + 1][c4];
        float4 s2 = *(float4*)&sT[r0 + 2][c4];
        float4 s3 = *(float4*)&sT[r0 + 3][c4];
        float4 s4 = *(float4*)&sT[r0 + 4][c4];
        float4 s5 = *(float4*)&sT[r0 + 5][c4];
        float4 p01 = fmax4(s0, s1), p23 = fmax4(s2, s3), p45 = fmax4(s4, s5);
        float4 v0 = fmax4(fmax4(p01, p23), s4);   // max(s0..s4)
        float4 v1 = fmax4(fmax4(p23, p45), s1);   // max(s1..s5)
        *(float4*)&vm[r0 + 0][c4] = v0;
        *(float4*)&vm[r0 + 1][c4] = v1;
    }
    __syncthreads();

    // ---- P3: horizontal 5-max in registers + peak test + emit -------------
    {
        int ty = tid >> 3, tx4 = (tid & 7) * 4;
        float2 va = *(float2*)&vm[ty][tx4 + 2];
        float4 vb = *(float4*)&vm[ty][tx4 + 4];
        float2 vc = *(float2*)&vm[ty][tx4 + 8];
        float a0 = va.x, a1 = va.y, a2 = vb.x, a3 = vb.y,
              a4 = vb.z, a5 = vb.w, a6 = vc.x, a7 = vc.y;
        float p01 = fmaxf(a0, a1), p12 = fmaxf(a1, a2), p23 = fmaxf(a2, a3),
              p34 = fmaxf(a3, a4), p45 = fmaxf(a4, a5), p56 = fmaxf(a5, a6);
        float o0 = fmaxf(fmaxf(p01, p23), a4);
        float o1 = fmaxf(fmaxf(p12, p34), a5);
        float o2 = fmaxf(fmaxf(p23, p45), a6);
        float o3 = fmaxf(fmaxf(p34, p56), a7);
        float4 ctr = *(float4*)&sT[ty + 2][tx4 + 4];
        float o[4] = { o0, o1, o2, o3 };
        float c[4] = { ctr.x, ctr.y, ctr.z, ctr.w };
        #pragma unroll
        for (int j = 0; j < 4; ++j) {
            if (c[j] > SCORES_TH && c[j] == o[j]) {
                unsigned idx = (unsigned)((y0 + ty) * W + (x0 + tx4 + j));
                unsigned long long key =
                    ((unsigned long long)__float_as_uint(c[j]) << 32) | (unsigned)(~idx);
                unsigned p = atomicAdd(&lcnt, 1u);
                if (p < CBUF) cbuf[p] = key;
            }
        }
    }
    __syncthreads();

    // ---- P4: one global atomic per block, coalesced flush -----------------
    unsigned n = lcnt; if (n > CBUF) n = CBUF;
    if (tid == 0) lbase = atomicAdd(&counts[b * CSTRIDE], n);
    __syncthreads();
    unsigned base = lbase;
    for (unsigned k = tid; k < n; k += 256)
        if (base + k < CAP) cand[(size_t)b * CAP + base + k] = cbuf[k];
}

// ---------------------------------------------------------------------------
// K2: fused LDS-histogram + suffix-sum scan + threshold + publish G + scatter
// (LDS cursors). One block per batch. I[bk] = #{keys in buckets >= bk};
// segment of bucket bk = [I[bk+1], I[bk]).
// ---------------------------------------------------------------------------
__global__ __launch_bounds__(1024) void scan_scatter(
    const unsigned* __restrict__ counts,
    const unsigned long long* __restrict__ cand,
    unsigned* __restrict__ G,
    unsigned* __restrict__ selC,
    unsigned long long* __restrict__ sel)
{
    const int b = blockIdx.x;
    __shared__ unsigned I[NB2 + 1];   // 39.3 KB
    __shared__ unsigned csum[1024];
    __shared__ int Tsh;
    const int tid = threadIdx.x;

    for (int i = tid; i < NB2 + 1; i += 1024) I[i] = 0;
    if (tid == 0) Tsh = 0;
    __syncthreads();

    unsigned M = counts[b * CSTRIDE]; if (M > CAP) M = CAP;
    const unsigned long long* cb = cand + (size_t)b * CAP;

    // LDS histogram
    for (unsigned i = tid; i < M; i += 1024) {
        unsigned bits = (unsigned)(cb[i] >> 32);
        int bk = (int)(bits >> 11) - OFFB2;
        bk = bk < 0 ? 0 : (bk > NB2 - 1 ? NB2 - 1 : bk);
        atomicAdd(&I[bk], 1u);
    }
    __syncthreads();

    // suffix-sum over descending bk; r = NB2-1-bk, chunk of SCHUNK per thread
    unsigned local = 0;
    #pragma unroll
    for (int u = 0; u < SCHUNK; ++u) {
        int r = tid * SCHUNK + u;
        if (r < NB2) local += I[NB2 - 1 - r];
    }
    csum[tid] = local;
    __syncthreads();
    for (int off = 1; off < 1024; off <<= 1) {      // Hillis-Steele inclusive
        unsigned v = (tid >= off) ? csum[tid - off] : 0u;
        __syncthreads();
        csum[tid] += v;
        __syncthreads();
    }
    unsigned run = (tid == 0) ? 0u : csum[tid - 1];
    #pragma unroll
    for (int u = 0; u < SCHUNK; ++u) {
        int r = tid * SCHUNK + u;
        if (r < NB2) {
            int bk = NB2 - 1 - r;
            run += I[bk];
            I[bk] = run;          // I becomes inclusive suffix sum
        }
    }
    __syncthreads();

    // T = max bk with I[bk] >= TOPK (0 if total < TOPK -> select all)
    int localT = -1;
    #pragma unroll
    for (int u = 0; u < SCHUNK; ++u) {
        int r = tid * SCHUNK + u;
        if (r < NB2) {
            int bk = NB2 - 1 - r;
            if (I[bk] >= TOPK && bk > localT) localT = bk;
        }
    }
    if (localT >= 0) atomicMax(&Tsh, localT);
    __syncthreads();
    const int T = Tsh;
    if (tid == 0) selC[b] = I[T];

    // publish clean segment table G, then scatter with LDS cursors
    unsigned* Gb = G + (size_t)b * GS2;
    for (int i = tid; i < NB2 + 1; i += 1024) Gb[i] = I[i];
    __syncthreads();

    for (unsigned i = tid; i < M; i += 1024) {
        unsigned long long key = cb[i];
        unsigned bits = (unsigned)(key >> 32);
        int bk = (int)(bits >> 11) - OFFB2;
        bk = bk < 0 ? 0 : (bk > NB2 - 1 ? NB2 - 1 : bk);
        if (bk >= T) {
            unsigned p = atomicAdd(&I[bk + 1], 1u);   // LDS cursor
            if (p < SELCAP) sel[(size_t)b * SELCAP + p] = key;
        }
    }
}

// ---------------------------------------------------------------------------
// K3: two-level exact rank, 4 lanes/key: rank = G[bk+1] + #{same-bucket keys
// > mine}; 25-cell softmax split across lanes; zero-fills ranks [C, TOPK)
// (replaces the d_out memset dispatch).
// ---------------------------------------------------------------------------
__global__ __launch_bounds__(256) void rank_refine(
    const float* __restrict__ s,
    const unsigned long long* __restrict__ sel,
    const unsigned* __restrict__ selC,
    const unsigned* __restrict__ G,
    float* __restrict__ out)
{
    const int b = blockIdx.y;
    unsigned C = selC[b]; if (C > SELCAP) C = SELCAP;
    const int tid = threadIdx.x;
    const unsigned g = blockIdx.x * 64u + (unsigned)(tid >> 2);
    const int l = tid & 3;

    if (g >= C) {                     // zero-fill unclaimed output ranks
        if (g < TOPK && l == 0) {
            out[((size_t)b * TOPK + g) * 2 + 0] = 0.0f;
            out[((size_t)b * TOPK + g) * 2 + 1] = 0.0f;
            out[(size_t)B * TOPK * 2 + (size_t)b * TOPK + g] = 0.0f;
        }
        return;
    }

    const unsigned long long* sb = sel + (size_t)b * SELCAP;
    const unsigned long long my = sb[g];
    unsigned bits = (unsigned)(my >> 32);
    int bk = (int)(bits >> 11) - OFFB2;
    bk = bk < 0 ? 0 : (bk > NB2 - 1 ? NB2 - 1 : bk);

    const unsigned* Gb = G + (size_t)b * GS2;
    unsigned start = Gb[bk + 1], end = Gb[bk];
    if (end > SELCAP) end = SELCAP;
    unsigned rank = 0;
    for (unsigned j = start + (unsigned)l; j < end; j += 4)
        rank += (sb[j] > my) ? 1u : 0u;

    float v = __uint_as_float(bits);
    unsigned idx = ~((unsigned)my);
    int y = (int)(idx >> 10), x = (int)(idx & 1023);
    const float* smb = s + (size_t)b * (H * W);
    float wsum = 0.f, ox = 0.f, oy = 0.f;
    for (int c = l; c < 25; c += 4) {
        int dy = c / 5 - 2, dx = c - (c / 5) * 5 - 2;
        int yy = y + dy, xx = x + dx;
        bool inb = (yy >= 0 && yy < H && xx >= 0 && xx < W);
        int yc = min(max(yy, 0), H - 1), xc = min(max(xx, 0), W - 1);
        float p = smb[yc * W + xc];
        float lg = inb ? p * 10.0f : -1e9f;   // 1/TEMPERATURE = 10
        float e = expf(lg);
        wsum += e; ox += e * (float)dx; oy += e * (float)dy;
    }
    rank += __shfl_xor(rank, 1); rank += __shfl_xor(rank, 2);
    wsum += __shfl_xor(wsum, 1); wsum += __shfl_xor(wsum, 2);
    ox   += __shfl_xor(ox, 1);   ox   += __shfl_xor(ox, 2);
    oy   += __shfl_xor(oy, 1);   oy   += __shfl_xor(oy, 2);

    unsigned frank = start + rank;
    if (l == 0 && frank < TOPK) {
        float offx = ox / wsum, offy = oy / wsum;
        out[((size_t)b * TOPK + frank) * 2 + 0] = (float)x + offx;
        out[((size_t)b * TOPK + frank) * 2 + 1] = (float)y + offy;
        out[(size_t)B * TOPK * 2 + (size_t)b * TOPK + frank] = v;
    }
}

// ---------------------------------------------------------------------------
extern "C" void kernel_launch(void* const* d_in, const int* in_sizes, int n_in,
                              void* d_out, int out_size, void* d_ws, size_t ws_size,
                              hipStream_t stream)
{
    const float* s = (const float*)d_in[0];
    float* out = (float*)d_out;
    char* ws = (char*)d_ws;

    size_t off = 0;
    unsigned* counts        = (unsigned*)(ws + off);  off += 2048;   // B*CSTRIDE*4
    unsigned* selC          = (unsigned*)(ws + off);  off += 64;
    unsigned* G             = (unsigned*)(ws + off);  off += (size_t)B * GS2 * 4;  // 630 KB
    unsigned long long* sel = (unsigned long long*)(ws + off); off += (size_t)B * SELCAP * 8; // 1 MB
    unsigned long long* cand= (unsigned long long*)(ws + off);                     // 8.4 MB

    hipMemsetAsync(counts, 0, 2048, stream);

    nms_compact<<<dim3(32, 32, B), dim3(256), 0, stream>>>(s, counts, cand);
    scan_scatter<<<dim3(B), dim3(1024), 0, stream>>>(counts, cand, G, selC, sel);
    rank_refine<<<dim3(SELCAP * 4 / 256, B), dim3(256), 0, stream>>>(s, sel, selC, G, out);
}

// Round 14
// 96.477 us; speedup vs baseline: 2.0527x; 1.3882x over previous
//
#include <hip/hip_runtime.h>
#include <math.h>

// Problem constants
#define B 16
#define H 1024
#define W 1024
#define TOPK 5000
#define SCORES_TH 0.2f

// selection pipeline constants
#define CAP 65536          // max candidates per batch (expected ~42k)
#define SELCAP 8192        // max selected per batch
#define NB2 9831           // buckets over value bits[31:11]
#define OFFB2 510361       // bits(0.2f) >> 11
#define GS2 9840           // padded per-batch stride for G (>= NB2+1)
#define SCHUNK 10          // ceil(NB2/1024)
#define CSTRIDE 32         // counts padded 128 B apart

// wave-NMS geometry
#define XSTRIPS 9          // ceil(1024/124)
#define YSTRIPS 32
#define SROWS 32           // output rows per wave
#define SCOLS 124          // output cols per wave (64 lanes x 2 - 4 halo)
#define WCAP 256           // per-wave LDS key buffer (expected ~159/strip)

// ---------------------------------------------------------------------------
// K1: wave-synchronous single 5x5 NMS (== double NMS, proven identity).
// No __syncthreads, no tile LDS. Each wave streams a 124x32 strip:
// per row: float2 load, shared pair-max + 4 shfls -> horizontal 5-max,
// 5-deep register ring -> vertical 5-max, peak==center test, emit to
// per-wave LDS buffer; one global atomic per wave at flush.
// Keys: (value_bits << 32) | ~idx  (desc value, asc index) — unique per pixel.
// ---------------------------------------------------------------------------
__global__ __launch_bounds__(256) void nms_wave(
    const float* __restrict__ s,
    unsigned* __restrict__ counts,
    unsigned long long* __restrict__ cand)
{
    __shared__ unsigned long long wbuf[4][WCAP];   // 8 KB, wave-private slices
    __shared__ unsigned wcnt[4];

    const int tid  = threadIdx.x;
    const int w    = tid >> 6;                     // wave within block
    const int lane = tid & 63;
    const int gw   = blockIdx.x * 4 + w;           // 0 .. 4607
    const int xs   = gw % XSTRIPS;
    const int t    = gw / XSTRIPS;                 // 0 .. 511
    const int ys   = t & 31;
    const int b    = t >> 5;

    if (lane == 0) wcnt[w] = 0;

    const float* sb = s + (size_t)b * (H * W);
    const int c0 = xs * SCOLS - 2 + 2 * lane;      // this lane's first col
    const int y0 = ys * SROWS;
    const bool in0  = (c0 >= 0) & (c0 < W);
    const bool in1  = (c0 + 1 >= 0) & (c0 + 1 < W);
    const bool fast = in0 & in1;                   // float2 path (all interior strips)
    const bool emitlane = (lane >= 1) & (lane <= 62);

    // vertical rings (named regs only — no runtime indexing)
    float ha0 = -INFINITY, ha1 = -INFINITY, ha2 = -INFINITY, ha3 = -INFINITY;
    float hb0 = -INFINITY, hb1 = -INFINITY, hb2 = -INFINITY, hb3 = -INFINITY;
    float va1 = -INFINITY, va2 = -INFINITY;        // center history (1-back, 2-back)
    float vb1 = -INFINITY, vb2 = -INFINITY;

    #pragma unroll 4
    for (int gy = y0 - 2; gy <= y0 + SROWS + 1; ++gy) {
        // ---- load row ------------------------------------------------------
        float a, bq;
        const bool yin = (gy >= 0) & (gy < H);
        if (yin & fast) {
            float2 v = *(const float2*)(sb + (size_t)gy * W + c0);
            a = v.x; bq = v.y;
        } else {
            a  = (yin & in0) ? sb[(size_t)gy * W + c0]     : -INFINITY;
            bq = (yin & in1) ? sb[(size_t)gy * W + c0 + 1] : -INFINITY;
        }

        // ---- horizontal 5-max via shfl -------------------------------------
        float p   = fmaxf(a, bq);
        float pm1 = __shfl_up(p, 1);               // p[l-1]
        float pp1 = __shfl_down(p, 1);             // p[l+1]
        float ap1 = __shfl_down(a, 1);             // a[l+1]
        float bm1 = __shfl_up(bq, 1);              // b[l-1]
        float hma = fmaxf(fmaxf(pm1, p), ap1);     // 5-max centered at c0
        float hmb = fmaxf(fmaxf(bm1, p), pp1);     // 5-max centered at c0+1

        // ---- emit output row r = gy-2 --------------------------------------
        if (gy >= y0 + 2) {
            float vma = fmaxf(fmaxf(fmaxf(ha0, ha1), fmaxf(ha2, ha3)), hma);
            float vmb = fmaxf(fmaxf(fmaxf(hb0, hb1), fmaxf(hb2, hb3)), hmb);
            bool pka = emitlane & in0 & (va2 > SCORES_TH) & (va2 == vma);
            bool pkb = emitlane & in1 & (vb2 > SCORES_TH) & (vb2 == vmb);
            if (pka | pkb) {
                int r = gy - 2;
                if (pka) {
                    unsigned idx = (unsigned)(r * W + c0);
                    unsigned long long key =
                        ((unsigned long long)__float_as_uint(va2) << 32) | (unsigned)(~idx);
                    unsigned pi = atomicAdd(&wcnt[w], 1u);
                    if (pi < WCAP) wbuf[w][pi] = key;
                    else {                          // overflow: direct reserved write
                        unsigned gp = atomicAdd(&counts[b * CSTRIDE], 1u);
                        if (gp < CAP) cand[(size_t)b * CAP + gp] = key;
                    }
                }
                if (pkb) {
                    unsigned idx = (unsigned)(r * W + c0 + 1);
                    unsigned long long key =
                        ((unsigned long long)__float_as_uint(vb2) << 32) | (unsigned)(~idx);
                    unsigned pi = atomicAdd(&wcnt[w], 1u);
                    if (pi < WCAP) wbuf[w][pi] = key;
                    else {
                        unsigned gp = atomicAdd(&counts[b * CSTRIDE], 1u);
                        if (gp < CAP) cand[(size_t)b * CAP + gp] = key;
                    }
                }
            }
        }

        // ---- shift rings ----------------------------------------------------
        ha0 = ha1; ha1 = ha2; ha2 = ha3; ha3 = hma;
        hb0 = hb1; hb1 = hb2; hb2 = hb3; hb3 = hmb;
        va2 = va1; va1 = a;
        vb2 = vb1; vb1 = bq;
    }

    // ---- flush: one global atomic per wave, coalesced copy ------------------
    unsigned n = wcnt[w]; if (n > WCAP) n = WCAP;
    unsigned base = 0;
    if (lane == 0) base = atomicAdd(&counts[b * CSTRIDE], n);
    base = __shfl(base, 0);
    for (unsigned k = (unsigned)lane; k < n; k += 64)
        if (base + k < CAP) cand[(size_t)b * CAP + base + k] = wbuf[w][k];
}

// ---------------------------------------------------------------------------
// K2: fused LDS-histogram + suffix-sum scan + threshold + publish G + scatter
// (LDS cursors). One block per batch. FROZEN (round 13).
// I[bk] = #{keys in buckets >= bk}; segment of bucket bk = [I[bk+1], I[bk]).
// ---------------------------------------------------------------------------
__global__ __launch_bounds__(1024) void scan_scatter(
    const unsigned* __restrict__ counts,
    const unsigned long long* __restrict__ cand,
    unsigned* __restrict__ G,
    unsigned* __restrict__ selC,
    unsigned long long* __restrict__ sel)
{
    const int b = blockIdx.x;
    __shared__ unsigned I[NB2 + 1];   // 39.3 KB
    __shared__ unsigned csum[1024];
    __shared__ int Tsh;
    const int tid = threadIdx.x;

    for (int i = tid; i < NB2 + 1; i += 1024) I[i] = 0;
    if (tid == 0) Tsh = 0;
    __syncthreads();

    unsigned M = counts[b * CSTRIDE]; if (M > CAP) M = CAP;
    const unsigned long long* cb = cand + (size_t)b * CAP;

    for (unsigned i = tid; i < M; i += 1024) {
        unsigned bits = (unsigned)(cb[i] >> 32);
        int bk = (int)(bits >> 11) - OFFB2;
        bk = bk < 0 ? 0 : (bk > NB2 - 1 ? NB2 - 1 : bk);
        atomicAdd(&I[bk], 1u);
    }
    __syncthreads();

    unsigned local = 0;
    #pragma unroll
    for (int u = 0; u < SCHUNK; ++u) {
        int r = tid * SCHUNK + u;
        if (r < NB2) local += I[NB2 - 1 - r];
    }
    csum[tid] = local;
    __syncthreads();
    for (int off = 1; off < 1024; off <<= 1) {      // Hillis-Steele inclusive
        unsigned v = (tid >= off) ? csum[tid - off] : 0u;
        __syncthreads();
        csum[tid] += v;
        __syncthreads();
    }
    unsigned run = (tid == 0) ? 0u : csum[tid - 1];
    #pragma unroll
    for (int u = 0; u < SCHUNK; ++u) {
        int r = tid * SCHUNK + u;
        if (r < NB2) {
            int bk = NB2 - 1 - r;
            run += I[bk];
            I[bk] = run;          // I becomes inclusive suffix sum
        }
    }
    __syncthreads();

    int localT = -1;
    #pragma unroll
    for (int u = 0; u < SCHUNK; ++u) {
        int r = tid * SCHUNK + u;
        if (r < NB2) {
            int bk = NB2 - 1 - r;
            if (I[bk] >= TOPK && bk > localT) localT = bk;
        }
    }
    if (localT >= 0) atomicMax(&Tsh, localT);
    __syncthreads();
    const int T = Tsh;
    if (tid == 0) selC[b] = I[T];

    unsigned* Gb = G + (size_t)b * GS2;
    for (int i = tid; i < NB2 + 1; i += 1024) Gb[i] = I[i];
    __syncthreads();

    for (unsigned i = tid; i < M; i += 1024) {
        unsigned long long key = cb[i];
        unsigned bits = (unsigned)(key >> 32);
        int bk = (int)(bits >> 11) - OFFB2;
        bk = bk < 0 ? 0 : (bk > NB2 - 1 ? NB2 - 1 : bk);
        if (bk >= T) {
            unsigned p = atomicAdd(&I[bk + 1], 1u);   // LDS cursor
            if (p < SELCAP) sel[(size_t)b * SELCAP + p] = key;
        }
    }
}

// ---------------------------------------------------------------------------
// K3: two-level exact rank, 4 lanes/key + zero-fill of ranks [C, TOPK).
// FROZEN (round 13).
// ---------------------------------------------------------------------------
__global__ __launch_bounds__(256) void rank_refine(
    const float* __restrict__ s,
    const unsigned long long* __restrict__ sel,
    const unsigned* __restrict__ selC,
    const unsigned* __restrict__ G,
    float* __restrict__ out)
{
    const int b = blockIdx.y;
    unsigned C = selC[b]; if (C > SELCAP) C = SELCAP;
    const int tid = threadIdx.x;
    const unsigned g = blockIdx.x * 64u + (unsigned)(tid >> 2);
    const int l = tid & 3;

    if (g >= C) {                     // zero-fill unclaimed output ranks
        if (g < TOPK && l == 0) {
            out[((size_t)b * TOPK + g) * 2 + 0] = 0.0f;
            out[((size_t)b * TOPK + g) * 2 + 1] = 0.0f;
            out[(size_t)B * TOPK * 2 + (size_t)b * TOPK + g] = 0.0f;
        }
        return;
    }

    const unsigned long long* sb = sel + (size_t)b * SELCAP;
    const unsigned long long my = sb[g];
    unsigned bits = (unsigned)(my >> 32);
    int bk = (int)(bits >> 11) - OFFB2;
    bk = bk < 0 ? 0 : (bk > NB2 - 1 ? NB2 - 1 : bk);

    const unsigned* Gb = G + (size_t)b * GS2;
    unsigned start = Gb[bk + 1], end = Gb[bk];
    if (end > SELCAP) end = SELCAP;
    unsigned rank = 0;
    for (unsigned j = start + (unsigned)l; j < end; j += 4)
        rank += (sb[j] > my) ? 1u : 0u;

    float v = __uint_as_float(bits);
    unsigned idx = ~((unsigned)my);
    int y = (int)(idx >> 10), x = (int)(idx & 1023);
    const float* smb = s + (size_t)b * (H * W);
    float wsum = 0.f, ox = 0.f, oy = 0.f;
    for (int c = l; c < 25; c += 4) {
        int dy = c / 5 - 2, dx = c - (c / 5) * 5 - 2;
        int yy = y + dy, xx = x + dx;
        bool inb = (yy >= 0 && yy < H && xx >= 0 && xx < W);
        int yc = min(max(yy, 0), H - 1), xc = min(max(xx, 0), W - 1);
        float p = smb[yc * W + xc];
        float lg = inb ? p * 10.0f : -1e9f;   // 1/TEMPERATURE = 10
        float e = expf(lg);
        wsum += e; ox += e * (float)dx; oy += e * (float)dy;
    }
    rank += __shfl_xor(rank, 1); rank += __shfl_xor(rank, 2);
    wsum += __shfl_xor(wsum, 1); wsum += __shfl_xor(wsum, 2);
    ox   += __shfl_xor(ox, 1);   ox   += __shfl_xor(ox, 2);
    oy   += __shfl_xor(oy, 1);   oy   += __shfl_xor(oy, 2);

    unsigned frank = start + rank;
    if (l == 0 && frank < TOPK) {
        float offx = ox / wsum, offy = oy / wsum;
        out[((size_t)b * TOPK + frank) * 2 + 0] = (float)x + offx;
        out[((size_t)b * TOPK + frank) * 2 + 1] = (float)y + offy;
        out[(size_t)B * TOPK * 2 + (size_t)b * TOPK + frank] = v;
    }
}

// ---------------------------------------------------------------------------
extern "C" void kernel_launch(void* const* d_in, const int* in_sizes, int n_in,
                              void* d_out, int out_size, void* d_ws, size_t ws_size,
                              hipStream_t stream)
{
    const float* s = (const float*)d_in[0];
    float* out = (float*)d_out;
    char* ws = (char*)d_ws;

    size_t off = 0;
    unsigned* counts        = (unsigned*)(ws + off);  off += 2048;   // B*CSTRIDE*4
    unsigned* selC          = (unsigned*)(ws + off);  off += 64;
    unsigned* G             = (unsigned*)(ws + off);  off += (size_t)B * GS2 * 4;  // 630 KB
    unsigned long long* sel = (unsigned long long*)(ws + off); off += (size_t)B * SELCAP * 8; // 1 MB
    unsigned long long* cand= (unsigned long long*)(ws + off);                     // 8.4 MB

    hipMemsetAsync(counts, 0, 2048, stream);

    nms_wave<<<dim3(XSTRIPS * YSTRIPS * B / 4), dim3(256), 0, stream>>>(s, counts, cand);
    scan_scatter<<<dim3(B), dim3(1024), 0, stream>>>(counts, cand, G, selC, sel);
    rank_refine<<<dim3(SELCAP * 4 / 256, B), dim3(256), 0, stream>>>(s, sel, selC, G, out);
}